// Round 2
// baseline (115.576 us; speedup 1.0000x reference)
//
#include <hip/hip_runtime.h>
#include <stdint.h>

#define HH 512
#define WW 512
#define CC 4
#define BB 8
#define NPIX (BB * HH * WW)   // 2097152
#define NBLKC (BB * HH)       // 4096 = k_cols grid (one row per block)

// min over 4 packed u8 row-distances, squared (exact integers in fp32)
__device__ __forceinline__ float row_min_sq(uint32_t v) {
    float c0 = (float)(v & 255u);
    float c1 = (float)((v >> 8) & 255u);
    float c2 = (float)((v >> 16) & 255u);
    float c3 = (float)(v >> 24);
    return fminf(fminf(c0 * c0, c1 * c1), fminf(c2 * c2, c3 * c3));
}

// exact zero-byte mask (no cross-byte borrow false-positives):
// byte==0  ->  that byte becomes 0xFF in the result
__device__ __forceinline__ uint32_t own_mask(uint32_t v) {
    uint32_t z = (~((v & 0x7F7F7F7Fu) + 0x7F7F7F7Fu)) & ~v & 0x80808080u;
    return (z >> 7) * 255u;
}

__device__ __forceinline__ uint32_t pk_bf16(float a, float b) {
    uint32_t ua = __builtin_bit_cast(uint32_t, a);
    uint32_t ub = __builtin_bit_cast(uint32_t, b);
    ua = (ua + 0x7FFFu + ((ua >> 16) & 1u)) >> 16;   // RNE, no NaN possible
    ub = (ub + 0x7FFFu + ((ub >> 16) & 1u)) >> 16;
    return ua | (ub << 16);
}

// ---------------------------------------------------------------------------
// K_rows: per-pixel CE (bf16) and per-row/per-class 1D distance (u8x4).
// One wave per image row; lane l owns columns [8l, 8l+8).
// ---------------------------------------------------------------------------
__global__ __launch_bounds__(256) void k_rows(const float* __restrict__ pred,
                                              const float* __restrict__ target,
                                              uint16_t* __restrict__ pp,
                                              uint32_t* __restrict__ gout) {
    const int tid  = threadIdx.x;
    const int wid  = tid >> 6;
    const int lane = tid & 63;
    const int row  = (blockIdx.x << 2) + wid;   // 0..4095 = b*512 + i
    const int b    = row >> 9;
    const int i    = row & 511;
    const int j0   = lane << 3;
    const size_t px = ((size_t)row << 9) + (size_t)j0;                 // pixel index
    const size_t pb = ((((size_t)b * CC) * HH + (size_t)i) << 9) + j0; // pred[b][0][i][j0]

    // load pred (4 channels x 8 columns)
    float x[CC][8];
    #pragma unroll
    for (int c = 0; c < CC; ++c) {
        const float4* p = reinterpret_cast<const float4*>(pred + pb + (size_t)c * (HH * WW));
        float4 a0 = p[0], a1 = p[1];
        x[c][0] = a0.x; x[c][1] = a0.y; x[c][2] = a0.z; x[c][3] = a0.w;
        x[c][4] = a1.x; x[c][5] = a1.y; x[c][6] = a1.z; x[c][7] = a1.w;
    }

    // labels = argmax(target) (one-hot; strict > keeps first-max semantics)
    int L[8];
    {
        float tm[8];
        #pragma unroll
        for (int c = 0; c < CC; ++c) {
            const float4* p = reinterpret_cast<const float4*>(target + pb + (size_t)c * (HH * WW));
            float4 a0 = p[0], a1 = p[1];
            float tv[8] = {a0.x, a0.y, a0.z, a0.w, a1.x, a1.y, a1.z, a1.w};
            #pragma unroll
            for (int jj = 0; jj < 8; ++jj) {
                if (c == 0) { tm[jj] = tv[jj]; L[jj] = 0; }
                else if (tv[jj] > tm[jj]) { tm[jj] = tv[jj]; L[jj] = c; }
            }
        }
    }

    // per-pixel cross entropy: lse - pred[label], stored bf16
    float ppv[8];
    #pragma unroll
    for (int jj = 0; jj < 8; ++jj) {
        float m = fmaxf(fmaxf(x[0][jj], x[1][jj]), fmaxf(x[2][jj], x[3][jj]));
        float s = __expf(x[0][jj] - m) + __expf(x[1][jj] - m) +
                  __expf(x[2][jj] - m) + __expf(x[3][jj] - m);
        float xs = (L[jj] == 0) ? x[0][jj] : (L[jj] == 1) ? x[1][jj]
                 : (L[jj] == 2) ? x[2][jj] : x[3][jj];
        ppv[jj] = (m + __logf(s)) - xs;
    }
    *reinterpret_cast<uint4*>(pp + px) =
        make_uint4(pk_bf16(ppv[0], ppv[1]), pk_bf16(ppv[2], ppv[3]),
                   pk_bf16(ppv[4], ppv[5]), pk_bf16(ppv[6], ppv[7]));

    // per-class 1D row distance via wave prefix scans
    uint32_t gp[8] = {0, 0, 0, 0, 0, 0, 0, 0};
    #pragma unroll
    for (int c = 0; c < CC; ++c) {
        // left: last feature index <= j
        int run = -1000000;
        int lastL[8];
        #pragma unroll
        for (int jj = 0; jj < 8; ++jj) { if (L[jj] == c) run = j0 + jj; lastL[jj] = run; }
        int incl = run;
        #pragma unroll
        for (int d = 1; d < 64; d <<= 1) {
            int up = __shfl_up(incl, (unsigned)d, 64);
            if (lane >= d) incl = max(incl, up);
        }
        int excl = __shfl_up(incl, 1u, 64);
        if (lane == 0) excl = -1000000;

        // right: next feature index >= j
        int nrun = 1000000;
        int nxtL[8];
        #pragma unroll
        for (int jj = 7; jj >= 0; --jj) { if (L[jj] == c) nrun = j0 + jj; nxtL[jj] = nrun; }
        int rincl = nrun;
        #pragma unroll
        for (int d = 1; d < 64; d <<= 1) {
            int dn = __shfl_down(rincl, (unsigned)d, 64);
            if (lane < 64 - d) rincl = min(rincl, dn);
        }
        int rexcl = __shfl_down(rincl, 1u, 64);
        if (lane == 63) rexcl = 1000000;

        #pragma unroll
        for (int jj = 0; jj < 8; ++jj) {
            int last = max(lastL[jj], excl);
            int nxt  = min(nxtL[jj], rexcl);
            int dl = (j0 + jj) - last;
            int dr = nxt - (j0 + jj);
            int gg = min(min(dl, dr), 255);   // >255 -> exp(-1300)=0 either way
            gp[jj] |= ((uint32_t)gg) << (c * 8);
        }
    }
    uint4* go = reinterpret_cast<uint4*>(gout + px);
    go[0] = make_uint4(gp[0], gp[1], gp[2], gp[3]);
    go[1] = make_uint4(gp[4], gp[5], gp[6], gp[7]);
}

// ---------------------------------------------------------------------------
// K_cols: vertical min-plus with outward early-exit, weight, CE combine,
// per-block partials + fused last-block final reduction.
// One block per image row; thread t owns columns 2t, 2t+1.
// ---------------------------------------------------------------------------
__global__ __launch_bounds__(256) void k_cols(const uint16_t* __restrict__ pp,
                                              const uint32_t* __restrict__ g,
                                              float* __restrict__ partial,
                                              unsigned int* __restrict__ counter,
                                              float* __restrict__ out) {
    const int bid = blockIdx.x;          // b*512 + i
    const int tid = threadIdx.x;
    const int i  = bid & 511;
    const int b  = bid >> 9;
    const int j  = tid << 1;
    const size_t rowbase = ((size_t)bid) << 9;

    uint32_t ppw = *reinterpret_cast<const uint32_t*>(pp + rowbase + j);
    float pp0 = __builtin_bit_cast(float, (ppw & 0xFFFFu) << 16);
    float pp1 = __builtin_bit_cast(float, ppw & 0xFFFF0000u);

    const uint32_t* gb = g + (((size_t)b) << 18) + (size_t)j;
    uint2 gown = *reinterpret_cast<const uint2*>(gb + ((size_t)i << 9));
    const uint32_t om0 = own_mask(gown.x);
    const uint32_t om1 = own_mask(gown.y);

    float best0 = row_min_sq(gown.x | om0);
    float best1 = row_min_sq(gown.y | om1);

    for (int dk = 1; dk < 512; ++dk) {
        float dk2 = (float)(dk * dk);
        if (!__any(dk2 < fmaxf(best0, best1))) break;  // all future cands >= dk^2
        int ku = i - dk;
        if (ku >= 0) {
            uint2 v = *reinterpret_cast<const uint2*>(gb + ((size_t)ku << 9));
            best0 = fminf(best0, row_min_sq(v.x | om0) + dk2);
            best1 = fminf(best1, row_min_sq(v.y | om1) + dk2);
        }
        int kd = i + dk;
        if (kd < 512) {
            uint2 v = *reinterpret_cast<const uint2*>(gb + ((size_t)kd << 9));
            best0 = fminf(best0, row_min_sq(v.x | om0) + dk2);
            best1 = fminf(best1, row_min_sq(v.y | om1) + dk2);
        }
    }

    // contrib = pp*(2 + 10*exp(-best/50))   [(d1+d2)^2 == best exactly]
    float v = pp0 * fmaf(10.0f, __expf(-0.02f * best0), 2.0f)
            + pp1 * fmaf(10.0f, __expf(-0.02f * best1), 2.0f);

    // block reduction
    #pragma unroll
    for (int off = 32; off > 0; off >>= 1) v += __shfl_down(v, (unsigned)off, 64);
    __shared__ float red[4];
    __shared__ int lastflag;
    const int wid = tid >> 6, lane = tid & 63;
    if (lane == 0) red[wid] = v;
    __syncthreads();
    if (tid == 0) {
        partial[bid] = (red[0] + red[1]) + (red[2] + red[3]);
        __threadfence();                                   // release partial[bid]
        unsigned int old = atomicAdd(counter, 1u);
        lastflag = (old == (unsigned int)(NBLKC - 1));
    }
    __syncthreads();

    if (lastflag) {
        __threadfence();                                   // acquire
        __shared__ double sd[256];
        double a = 0.0;
        for (int idx = tid; idx < NBLKC; idx += 256)
            a += (double)__hip_atomic_load(&partial[idx], __ATOMIC_RELAXED,
                                           __HIP_MEMORY_SCOPE_AGENT);
        sd[tid] = a;
        __syncthreads();
        #pragma unroll
        for (int s = 128; s > 0; s >>= 1) {
            if (tid < s) sd[tid] += sd[tid + s];
            __syncthreads();
        }
        if (tid == 0) out[0] = (float)(sd[0] * (1.0 / (double)NPIX));
    }
}

extern "C" void kernel_launch(void* const* d_in, const int* in_sizes, int n_in,
                              void* d_out, int out_size, void* d_ws, size_t ws_size,
                              hipStream_t stream) {
    const float* pred   = (const float*)d_in[0];
    const float* target = (const float*)d_in[1];
    char* ws = (char*)d_ws;
    // layout: pp bf16[NPIX] (4MB) | g u32[NPIX] (8MB) | partial f32[NBLKC] | counter u32
    uint16_t* pp      = (uint16_t*)ws;
    uint32_t* g       = (uint32_t*)(ws + (size_t)NPIX * 2);
    float*    partial = (float*)(ws + (size_t)NPIX * 6);
    unsigned int* counter = (unsigned int*)(ws + (size_t)NPIX * 6 + NBLKC * 4);
    float*    out     = (float*)d_out;

    hipMemsetAsync(counter, 0, 4, stream);
    hipLaunchKernelGGL(k_rows, dim3(4096 / 4), dim3(256), 0, stream, pred, target, pp, g);
    hipLaunchKernelGGL(k_cols, dim3(NBLKC), dim3(256), 0, stream, pp, g, partial, counter, out);
}

// Round 3
// 33.678 us; speedup vs baseline: 3.4318x; 3.4318x over previous
//
#include <hip/hip_runtime.h>
#include <stdint.h>

#define HH 512
#define WW 512
#define CC 4
#define BB 8
#define NPIX (BB * HH * WW)   // 2097152
#define NBLKC (BB * HH)       // 4096 = k_cols grid (one row per block)

// min over 4 packed u8 row-distances, squared (exact integers in fp32)
__device__ __forceinline__ float row_min_sq(uint32_t v) {
    float c0 = (float)(v & 255u);
    float c1 = (float)((v >> 8) & 255u);
    float c2 = (float)((v >> 16) & 255u);
    float c3 = (float)(v >> 24);
    return fminf(fminf(c0 * c0, c1 * c1), fminf(c2 * c2, c3 * c3));
}

// exact zero-byte mask (no cross-byte borrow false-positives):
// byte==0  ->  that byte becomes 0xFF in the result
__device__ __forceinline__ uint32_t own_mask(uint32_t v) {
    uint32_t z = (~((v & 0x7F7F7F7Fu) + 0x7F7F7F7Fu)) & ~v & 0x80808080u;
    return (z >> 7) * 255u;
}

__device__ __forceinline__ uint32_t pk_bf16(float a, float b) {
    uint32_t ua = __builtin_bit_cast(uint32_t, a);
    uint32_t ub = __builtin_bit_cast(uint32_t, b);
    ua = (ua + 0x7FFFu + ((ua >> 16) & 1u)) >> 16;   // RNE, no NaN possible
    ub = (ub + 0x7FFFu + ((ub >> 16) & 1u)) >> 16;
    return ua | (ub << 16);
}

// ---------------------------------------------------------------------------
// K_rows: per-pixel CE (bf16) and per-row/per-class 1D distance (u8x4).
// One wave per image row; lane l owns columns [8l, 8l+8).
// ---------------------------------------------------------------------------
__global__ __launch_bounds__(256) void k_rows(const float* __restrict__ pred,
                                              const float* __restrict__ target,
                                              uint16_t* __restrict__ pp,
                                              uint32_t* __restrict__ gout) {
    const int tid  = threadIdx.x;
    const int wid  = tid >> 6;
    const int lane = tid & 63;
    const int row  = (blockIdx.x << 2) + wid;   // 0..4095 = b*512 + i
    const int b    = row >> 9;
    const int i    = row & 511;
    const int j0   = lane << 3;
    const size_t px = ((size_t)row << 9) + (size_t)j0;                 // pixel index
    const size_t pb = ((((size_t)b * CC) * HH + (size_t)i) << 9) + j0; // pred[b][0][i][j0]

    // load pred (4 channels x 8 columns)
    float x[CC][8];
    #pragma unroll
    for (int c = 0; c < CC; ++c) {
        const float4* p = reinterpret_cast<const float4*>(pred + pb + (size_t)c * (HH * WW));
        float4 a0 = p[0], a1 = p[1];
        x[c][0] = a0.x; x[c][1] = a0.y; x[c][2] = a0.z; x[c][3] = a0.w;
        x[c][4] = a1.x; x[c][5] = a1.y; x[c][6] = a1.z; x[c][7] = a1.w;
    }

    // labels = argmax(target) (one-hot; strict > keeps first-max semantics)
    int L[8];
    {
        float tm[8];
        #pragma unroll
        for (int c = 0; c < CC; ++c) {
            const float4* p = reinterpret_cast<const float4*>(target + pb + (size_t)c * (HH * WW));
            float4 a0 = p[0], a1 = p[1];
            float tv[8] = {a0.x, a0.y, a0.z, a0.w, a1.x, a1.y, a1.z, a1.w};
            #pragma unroll
            for (int jj = 0; jj < 8; ++jj) {
                if (c == 0) { tm[jj] = tv[jj]; L[jj] = 0; }
                else if (tv[jj] > tm[jj]) { tm[jj] = tv[jj]; L[jj] = c; }
            }
        }
    }

    // per-pixel cross entropy: lse - pred[label], stored bf16
    float ppv[8];
    #pragma unroll
    for (int jj = 0; jj < 8; ++jj) {
        float m = fmaxf(fmaxf(x[0][jj], x[1][jj]), fmaxf(x[2][jj], x[3][jj]));
        float s = __expf(x[0][jj] - m) + __expf(x[1][jj] - m) +
                  __expf(x[2][jj] - m) + __expf(x[3][jj] - m);
        float xs = (L[jj] == 0) ? x[0][jj] : (L[jj] == 1) ? x[1][jj]
                 : (L[jj] == 2) ? x[2][jj] : x[3][jj];
        ppv[jj] = (m + __logf(s)) - xs;
    }
    *reinterpret_cast<uint4*>(pp + px) =
        make_uint4(pk_bf16(ppv[0], ppv[1]), pk_bf16(ppv[2], ppv[3]),
                   pk_bf16(ppv[4], ppv[5]), pk_bf16(ppv[6], ppv[7]));

    // per-class 1D row distance via wave prefix scans
    uint32_t gp[8] = {0, 0, 0, 0, 0, 0, 0, 0};
    #pragma unroll
    for (int c = 0; c < CC; ++c) {
        // left: last feature index <= j
        int run = -1000000;
        int lastL[8];
        #pragma unroll
        for (int jj = 0; jj < 8; ++jj) { if (L[jj] == c) run = j0 + jj; lastL[jj] = run; }
        int incl = run;
        #pragma unroll
        for (int d = 1; d < 64; d <<= 1) {
            int up = __shfl_up(incl, (unsigned)d, 64);
            if (lane >= d) incl = max(incl, up);
        }
        int excl = __shfl_up(incl, 1u, 64);
        if (lane == 0) excl = -1000000;

        // right: next feature index >= j
        int nrun = 1000000;
        int nxtL[8];
        #pragma unroll
        for (int jj = 7; jj >= 0; --jj) { if (L[jj] == c) nrun = j0 + jj; nxtL[jj] = nrun; }
        int rincl = nrun;
        #pragma unroll
        for (int d = 1; d < 64; d <<= 1) {
            int dn = __shfl_down(rincl, (unsigned)d, 64);
            if (lane < 64 - d) rincl = min(rincl, dn);
        }
        int rexcl = __shfl_down(rincl, 1u, 64);
        if (lane == 63) rexcl = 1000000;

        #pragma unroll
        for (int jj = 0; jj < 8; ++jj) {
            int last = max(lastL[jj], excl);
            int nxt  = min(nxtL[jj], rexcl);
            int dl = (j0 + jj) - last;
            int dr = nxt - (j0 + jj);
            int gg = min(min(dl, dr), 255);   // >255 -> exp(-1300)=0 either way
            gp[jj] |= ((uint32_t)gg) << (c * 8);
        }
    }
    uint4* go = reinterpret_cast<uint4*>(gout + px);
    go[0] = make_uint4(gp[0], gp[1], gp[2], gp[3]);
    go[1] = make_uint4(gp[4], gp[5], gp[6], gp[7]);
}

// ---------------------------------------------------------------------------
// K_cols: vertical min-plus. Unconditional dk<=2 prefix (one memory round
// trip resolves ~all pixels for random labels), rare break-loop fallback.
// One block per image row (XCD-swizzled); thread t owns columns 2t, 2t+1.
// ---------------------------------------------------------------------------
__global__ __launch_bounds__(256) void k_cols(const uint16_t* __restrict__ pp,
                                              const uint32_t* __restrict__ g,
                                              float* __restrict__ partial) {
    const int bid0 = blockIdx.x;
    // XCD-bijective swizzle (4096 % 8 == 0): XCD x owns batch x -> its g-slab
    // (1 MB) is L2-resident for the +-dk row revisits.
    const int bid = ((bid0 & 7) << 9) | (bid0 >> 3);
    const int tid = threadIdx.x;
    const int i  = bid & 511;
    const int b  = bid >> 9;
    const int j  = tid << 1;
    const size_t rowbase = ((size_t)bid) << 9;

    uint32_t ppw = *reinterpret_cast<const uint32_t*>(pp + rowbase + j);
    float pp0 = __builtin_bit_cast(float, (ppw & 0xFFFFu) << 16);
    float pp1 = __builtin_bit_cast(float, ppw & 0xFFFF0000u);

    const uint32_t* gb = g + (((size_t)b) << 18) + (size_t)j;
    uint2 gown = *reinterpret_cast<const uint2*>(gb + ((size_t)i << 9));
    const uint32_t om0 = own_mask(gown.x);
    const uint32_t om1 = own_mask(gown.y);

    float best0 = row_min_sq(gown.x | om0);
    float best1 = row_min_sq(gown.y | om1);

    // unconditional prefix dk = 1, 2 (branches are block-uniform; all loads
    // issue before the single waitcnt)
    #pragma unroll
    for (int dk = 1; dk <= 2; ++dk) {
        const float dk2 = (float)(dk * dk);
        int ku = i - dk;
        if (ku >= 0) {
            uint2 v = *reinterpret_cast<const uint2*>(gb + ((size_t)ku << 9));
            best0 = fminf(best0, row_min_sq(v.x | om0) + dk2);
            best1 = fminf(best1, row_min_sq(v.y | om1) + dk2);
        }
        int kd = i + dk;
        if (kd < 512) {
            uint2 v = *reinterpret_cast<const uint2*>(gb + ((size_t)kd << 9));
            best0 = fminf(best0, row_min_sq(v.x | om0) + dk2);
            best1 = fminf(best1, row_min_sq(v.y | om1) + dk2);
        }
    }

    // rare fallback: only if some pixel could still improve (dk2 >= 9 from here)
    if (__any(fmaxf(best0, best1) > 9.0f)) {
        for (int dk = 3; dk < 512; ++dk) {
            const float dk2 = (float)(dk * dk);
            if (!__any(dk2 < fmaxf(best0, best1))) break;
            int ku = i - dk;
            if (ku >= 0) {
                uint2 v = *reinterpret_cast<const uint2*>(gb + ((size_t)ku << 9));
                best0 = fminf(best0, row_min_sq(v.x | om0) + dk2);
                best1 = fminf(best1, row_min_sq(v.y | om1) + dk2);
            }
            int kd = i + dk;
            if (kd < 512) {
                uint2 v = *reinterpret_cast<const uint2*>(gb + ((size_t)kd << 9));
                best0 = fminf(best0, row_min_sq(v.x | om0) + dk2);
                best1 = fminf(best1, row_min_sq(v.y | om1) + dk2);
            }
        }
    }

    // contrib = pp*(2 + 10*exp(-best/50))   [(d1+d2)^2 == best exactly]
    float v = pp0 * fmaf(10.0f, __expf(-0.02f * best0), 2.0f)
            + pp1 * fmaf(10.0f, __expf(-0.02f * best1), 2.0f);

    // block reduction
    #pragma unroll
    for (int off = 32; off > 0; off >>= 1) v += __shfl_down(v, (unsigned)off, 64);
    __shared__ float red[4];
    const int wid = tid >> 6, lane = tid & 63;
    if (lane == 0) red[wid] = v;
    __syncthreads();
    if (tid == 0) partial[bid] = (red[0] + red[1]) + (red[2] + red[3]);
}

// ---------------------------------------------------------------------------
// K_red: deterministic double-precision final reduction.
// ---------------------------------------------------------------------------
__global__ __launch_bounds__(256) void k_red(const float* __restrict__ partial,
                                             float* __restrict__ out) {
    __shared__ double sd[256];
    double a = 0.0;
    for (int idx = threadIdx.x; idx < NBLKC; idx += 256) a += (double)partial[idx];
    sd[threadIdx.x] = a;
    __syncthreads();
    #pragma unroll
    for (int s = 128; s > 0; s >>= 1) {
        if (threadIdx.x < s) sd[threadIdx.x] += sd[threadIdx.x + s];
        __syncthreads();
    }
    if (threadIdx.x == 0) out[0] = (float)(sd[0] * (1.0 / (double)NPIX));
}

extern "C" void kernel_launch(void* const* d_in, const int* in_sizes, int n_in,
                              void* d_out, int out_size, void* d_ws, size_t ws_size,
                              hipStream_t stream) {
    const float* pred   = (const float*)d_in[0];
    const float* target = (const float*)d_in[1];
    char* ws = (char*)d_ws;
    // layout: pp bf16[NPIX] (4MB) | g u32[NPIX] (8MB) | partial f32[NBLKC]
    uint16_t* pp      = (uint16_t*)ws;
    uint32_t* g       = (uint32_t*)(ws + (size_t)NPIX * 2);
    float*    partial = (float*)(ws + (size_t)NPIX * 6);
    float*    out     = (float*)d_out;

    hipLaunchKernelGGL(k_rows, dim3(4096 / 4), dim3(256), 0, stream, pred, target, pp, g);
    hipLaunchKernelGGL(k_cols, dim3(NBLKC), dim3(256), 0, stream, pp, g, partial);
    hipLaunchKernelGGL(k_red, dim3(1), dim3(256), 0, stream, partial, out);
}